// Round 1
// 108.225 us; speedup vs baseline: 1.0202x; 1.0202x over previous
//
#include <hip/hip_runtime.h>
#include <math.h>

#define BB 8
#define NN 256
#define DD 128

typedef _Float16 h2 __attribute__((ext_vector_type(2)));
union U4 { uint4 u; float4 f; h2 h[8]; };

static __device__ __forceinline__ h2 relu2(h2 v) {
    h2 z = {(_Float16)0, (_Float16)0};
#if __has_builtin(__builtin_elementwise_max)
    return __builtin_elementwise_max(v, z);
#else
    v.x = v.x > z.x ? v.x : z.x;
    v.y = v.y > z.y ? v.y : z.y;
    return v;
#endif
}

static __device__ __forceinline__ float dot2acc(h2 a, h2 b, float c) {
#if __has_builtin(__builtin_amdgcn_fdot2)
    return __builtin_amdgcn_fdot2(a, b, c, false);
#else
    return fmaf((float)a.x, (float)b.x, fmaf((float)a.y, (float)b.y, c));
#endif
}

// ---------------- Kernel A: h = node@Wn+bn (f32), ti = node@We1[:D]+be1 (f16),
//                  aj = node@We1[D:2D] (f16). Block 0 also converts edge weights to f16.
#define PR 4
__global__ __launch_bounds__(256) void prep_kernel(
    const float* __restrict__ node, const float* __restrict__ Wn,
    const float* __restrict__ bn, const float* __restrict__ We1,
    const float* __restrict__ be1, const float* __restrict__ We2,
    float* __restrict__ h, _Float16* __restrict__ tih,
    _Float16* __restrict__ ajh, _Float16* __restrict__ wth)
{
    __shared__ __align__(16) float sx[PR * DD];
    __shared__ float s_acc[12 * 128];
    int tid = threadIdx.x;
    int cp = tid & 63;
    int rp = (tid >> 6) & 1;
    int ks = tid >> 7;
    int row0 = blockIdx.x * PR;
    if (tid < 128) {
        int rr = tid >> 5, cc = (tid & 31) << 2;
        *(float4*)&sx[rr * DD + cc] = *(const float4*)&node[(size_t)(row0 + rr) * DD + cc];
    }
    if (blockIdx.x == 0 && tid < 128) {
        wth[0 * 128 + tid] = (_Float16)We1[(size_t)(2 * DD + 0) * DD + tid];
        wth[1 * 128 + tid] = (_Float16)We1[(size_t)(2 * DD + 1) * DD + tid];
        wth[2 * 128 + tid] = (_Float16)We1[(size_t)(2 * DD + 2) * DD + tid];
        wth[3 * 128 + tid] = (_Float16)We2[tid];
    }
    __syncthreads();
    int d0 = cp << 1;
    int ra = rp << 1, rb = ra | 1;
    float ah[2] = {0.f, 0.f}, ai[2] = {0.f, 0.f}, ajc[2] = {0.f, 0.f};
    float bh[2] = {0.f, 0.f}, bi[2] = {0.f, 0.f}, bjc[2] = {0.f, 0.f};
    int k0 = ks << 6;
    for (int k = k0; k < k0 + 64; k += 4) {
        float4 xa = *(const float4*)&sx[ra * DD + k];
        float4 xb = *(const float4*)&sx[rb * DD + k];
        #pragma unroll
        for (int kk = 0; kk < 4; ++kk) {
            float2 w0 = *(const float2*)&Wn [(size_t)(k + kk) * DD + d0];
            float2 w1 = *(const float2*)&We1[(size_t)(k + kk) * DD + d0];
            float2 w2 = *(const float2*)&We1[(size_t)(DD + k + kk) * DD + d0];
            float xav = (kk == 0) ? xa.x : (kk == 1) ? xa.y : (kk == 2) ? xa.z : xa.w;
            float xbv = (kk == 0) ? xb.x : (kk == 1) ? xb.y : (kk == 2) ? xb.z : xb.w;
            ah[0] = fmaf(xav, w0.x, ah[0]); ah[1] = fmaf(xav, w0.y, ah[1]);
            ai[0] = fmaf(xav, w1.x, ai[0]); ai[1] = fmaf(xav, w1.y, ai[1]);
            ajc[0] = fmaf(xav, w2.x, ajc[0]); ajc[1] = fmaf(xav, w2.y, ajc[1]);
            bh[0] = fmaf(xbv, w0.x, bh[0]); bh[1] = fmaf(xbv, w0.y, bh[1]);
            bi[0] = fmaf(xbv, w1.x, bi[0]); bi[1] = fmaf(xbv, w1.y, bi[1]);
            bjc[0] = fmaf(xbv, w2.x, bjc[0]); bjc[1] = fmaf(xbv, w2.y, bjc[1]);
        }
    }
    int p = (rp << 6) | cp;
    if (ks == 1) {
        s_acc[0 * 128 + p] = ah[0];  s_acc[1 * 128 + p] = ah[1];
        s_acc[2 * 128 + p] = ai[0];  s_acc[3 * 128 + p] = ai[1];
        s_acc[4 * 128 + p] = ajc[0]; s_acc[5 * 128 + p] = ajc[1];
        s_acc[6 * 128 + p] = bh[0];  s_acc[7 * 128 + p] = bh[1];
        s_acc[8 * 128 + p] = bi[0];  s_acc[9 * 128 + p] = bi[1];
        s_acc[10 * 128 + p] = bjc[0]; s_acc[11 * 128 + p] = bjc[1];
    }
    __syncthreads();
    if (ks == 0) {
        float2 bn2  = *(const float2*)&bn[d0];
        float2 be12 = *(const float2*)&be1[d0];
        ah[0] += s_acc[0 * 128 + p] + bn2.x;  ah[1] += s_acc[1 * 128 + p] + bn2.y;
        ai[0] += s_acc[2 * 128 + p] + be12.x; ai[1] += s_acc[3 * 128 + p] + be12.y;
        ajc[0] += s_acc[4 * 128 + p];         ajc[1] += s_acc[5 * 128 + p];
        bh[0] += s_acc[6 * 128 + p] + bn2.x;  bh[1] += s_acc[7 * 128 + p] + bn2.y;
        bi[0] += s_acc[8 * 128 + p] + be12.x; bi[1] += s_acc[9 * 128 + p] + be12.y;
        bjc[0] += s_acc[10 * 128 + p];        bjc[1] += s_acc[11 * 128 + p];
        size_t oa = (size_t)(row0 + ra) * DD + d0;
        size_t ob = (size_t)(row0 + rb) * DD + d0;
        *(float2*)&h[oa] = make_float2(ah[0], ah[1]);
        *(float2*)&h[ob] = make_float2(bh[0], bh[1]);
        *(h2*)&tih[oa] = (h2){(_Float16)ai[0], (_Float16)ai[1]};
        *(h2*)&tih[ob] = (h2){(_Float16)bi[0], (_Float16)bi[1]};
        *(h2*)&ajh[oa] = (h2){(_Float16)ajc[0], (_Float16)ajc[1]};
        *(h2*)&ajh[ob] = (h2){(_Float16)bjc[0], (_Float16)bjc[1]};
    }
}

// ---------------- Kernel B (fused): IT=4 rows/block, 512 threads, grid 512.
// LDS ~70KB -> 2 blocks/CU (4 waves/SIMD) so the serial phase chain of one block
// overlaps the other block's compute. Full 64KB f16 aj tile staged per block;
// thread = (j = tid&255, half = tid>>8 -> rows 2h, 2h+1).
#define IT 4
__global__ __launch_bounds__(512, 4) void edge_kernel(
    const _Float16* __restrict__ tih, const _Float16* __restrict__ ajh,
    const _Float16* __restrict__ wth, const float* __restrict__ rel,
    const int* __restrict__ adj, const float* __restrict__ be2,
    const float* __restrict__ h, const float* __restrict__ Wa,
    const float* __restrict__ ba, const float* __restrict__ node,
    const float* __restrict__ gamma, const float* __restrict__ beta,
    float* __restrict__ out)
{
    __shared__ __align__(16) float s_buf[16384];   // 64KB: f16 aj tile / partial slots alias
    __shared__ __align__(16) float s_w[NN * 4];    // w transposed: [j][r], 4KB
    __shared__ __align__(16) float s_m[DD * 4];    // msg transposed: [k][r], 2KB
    __shared__ float s_redM[IT][4];
    __shared__ float s_redS[IT][4];
    __shared__ float s_red2[IT][2][2];

    int tid = threadIdx.x;
    int b  = blockIdx.x >> 6;                 // 64 blocks per batch
    int i0 = (blockIdx.x & 63) << 2;          // 4 rows
    int j    = tid & 255;
    int half = tid >> 8;                      // 0/1: rows 2*half, 2*half+1
    int rb   = half << 1;

    // ---- per-thread edge inputs for 2 rows
    const float2* rel2 = (const float2*)rel;
    float sc[2];
    int msk[2];
    h2 rxh[2], ryh[2], dsh[2];
    float be2v = be2[0];
    #pragma unroll
    for (int r = 0; r < 2; ++r) {
        float2 rp = rel2[(size_t)(b * NN + i0 + rb + r) * NN + j];
        float ds = sqrtf(rp.x * rp.x + rp.y * rp.y);
        _Float16 xh = (_Float16)rp.x, yh = (_Float16)rp.y, dh = (_Float16)ds;
        rxh[r] = (h2){xh, xh}; ryh[r] = (h2){yh, yh}; dsh[r] = (h2){dh, dh};
        msk[r] = adj[(size_t)(b * NN + i0 + rb + r) * NN + j];
        sc[r] = be2v;
    }

    // ---- stage full f16 aj tile (256 rows x 128 f16 = 64KB), XOR-swizzled 16B granules
    {
        const _Float16* AJH = ajh + (size_t)b * NN * DD;
        #pragma unroll
        for (int it = 0; it < 8; ++it) {
            int idx = tid + (it << 9);         // 0..4095 granules
            int rr = idx >> 4, g = idx & 15;
            float4 v = *(const float4*)&AJH[(size_t)rr * DD + (g << 3)];
            *(float4*)&s_buf[rr * 64 + ((g ^ (rr & 15)) << 2)] = v;
        }
    }
    // wave-uniform ti base -> scalar loads
    int tibase = __builtin_amdgcn_readfirstlane((b * NN + i0 + rb) * DD);
    const _Float16* TIH = tih + tibase;
    __syncthreads();                              // B0: tile ready

    // ---- Phase 1: scores (packed f16)
    #pragma unroll 4
    for (int gg = 0; gg < 16; ++gg) {
        U4 a; a.f = *(const float4*)&s_buf[j * 64 + ((gg ^ (j & 15)) << 2)];
        int dd = gg << 3;
        U4 w0u, w1u, w2u, e2u;
        w0u.u = *(const uint4*)&wth[0 * 128 + dd];
        w1u.u = *(const uint4*)&wth[1 * 128 + dd];
        w2u.u = *(const uint4*)&wth[2 * 128 + dd];
        e2u.u = *(const uint4*)&wth[3 * 128 + dd];
        #pragma unroll
        for (int r = 0; r < 2; ++r) {
            U4 t; t.u = *(const uint4*)&TIH[r * DD + dd];
            #pragma unroll
            for (int u = 0; u < 4; ++u) {
                h2 v = t.h[u] + a.h[u];
                v = rxh[r] * w0u.h[u] + v;
                v = ryh[r] * w1u.h[u] + v;
                v = dsh[r] * w2u.h[u] + v;
                v = relu2(v);
                sc[r] = dot2acc(v, e2u.h[u], sc[r]);
            }
        }
    }
    #pragma unroll
    for (int r = 0; r < 2; ++r) if (msk[r] == 0) sc[r] = -3.0e38f;

    // ---- Phase 2: masked softmax across j (4 waves per half)
    int wave = tid >> 6, wig = wave & 3, lane = tid & 63;
    float e[2];
    {
        float m[2];
        #pragma unroll
        for (int r = 0; r < 2; ++r) m[r] = sc[r];
        for (int off = 32; off > 0; off >>= 1) {
            #pragma unroll
            for (int r = 0; r < 2; ++r) m[r] = fmaxf(m[r], __shfl_xor(m[r], off));
        }
        if (lane == 0) {
            #pragma unroll
            for (int r = 0; r < 2; ++r) s_redM[rb + r][wig] = m[r];
        }
    }
    __syncthreads();                              // B1: maxes ready
    {
        float s[2];
        #pragma unroll
        for (int r = 0; r < 2; ++r) {
            float M = fmaxf(fmaxf(s_redM[rb + r][0], s_redM[rb + r][1]),
                            fmaxf(s_redM[rb + r][2], s_redM[rb + r][3]));
            e[r] = (msk[r] == 0) ? 0.f : __expf(sc[r] - M);
            s[r] = e[r];
        }
        for (int off = 32; off > 0; off >>= 1) {
            #pragma unroll
            for (int r = 0; r < 2; ++r) s[r] += __shfl_xor(s[r], off);
        }
        if (lane == 0) {
            #pragma unroll
            for (int r = 0; r < 2; ++r) s_redS[rb + r][wig] = s[r];
        }
    }
    __syncthreads();                              // B2: sums ready
    {
        float2 wq;
        #pragma unroll
        for (int r = 0; r < 2; ++r) {
            float S = s_redS[rb + r][0] + s_redS[rb + r][1] + s_redS[rb + r][2] + s_redS[rb + r][3];
            float wv = e[r] * __builtin_amdgcn_rcpf(S);
            ((float*)&wq)[r] = wv;
        }
        *(float2*)&s_w[(j << 2) + rb] = wq;       // [j][4 rows]
    }
    __syncthreads();                              // B3: s_w ready; tile dead (s_part alias safe)

    // ---- Phase 3: msg partials = w@h. Thread: g3=tid&31 (d4-group), sl=tid>>5 (16 j-slices of 16)
    float* s_part = s_buf;                        // stride-20 slots (80B, 16B-aligned)
    int g3 = tid & 31, sl = tid >> 5;
    {
        const float* hb = h + (size_t)b * NN * DD;
        float4 acc[4];
        #pragma unroll
        for (int r = 0; r < 4; ++r) acc[r] = make_float4(0.f, 0.f, 0.f, 0.f);
        for (int q = 0; q < 16; ++q) {
            int jj = (sl << 4) + q;
            float4 hv = *(const float4*)&hb[(size_t)jj * DD + (g3 << 2)];
            float4 wa = *(const float4*)&s_w[jj << 2];     // rows 0-3 (broadcast)
            #pragma unroll
            for (int r = 0; r < 4; ++r) {
                float wv = ((float*)&wa)[r];
                acc[r].x = fmaf(wv, hv.x, acc[r].x); acc[r].y = fmaf(wv, hv.y, acc[r].y);
                acc[r].z = fmaf(wv, hv.z, acc[r].z); acc[r].w = fmaf(wv, hv.w, acc[r].w);
            }
        }
        int base = ((sl << 5) + g3) * 20;
        #pragma unroll
        for (int r = 0; r < 4; ++r) *(float4*)&s_part[base + (r << 2)] = acc[r];
    }
    __syncthreads();                              // B4: partials ready
    int r5 = tid >> 7, d5 = tid & 127;
    {
        float s = 0.f;
        #pragma unroll
        for (int s2 = 0; s2 < 16; ++s2)
            s += s_part[((s2 << 5) + (d5 >> 2)) * 20 + (r5 << 2) + (d5 & 3)];
        s_m[(d5 << 2) + r5] = s;
    }
    __syncthreads();                              // B5: s_m ready; s_part reads done

    // ---- Phase 4: agg partials = msg@Wa. Thread: g3 (d4-group), sl (16 k-slices of 8)
    {
        float4 ac[4];
        #pragma unroll
        for (int r = 0; r < 4; ++r) ac[r] = make_float4(0.f, 0.f, 0.f, 0.f);
        for (int q = 0; q < 8; ++q) {
            int k = (sl << 3) + q;
            float4 wv = *(const float4*)&Wa[(size_t)k * DD + (g3 << 2)];
            float4 ma = *(const float4*)&s_m[k << 2];      // 4 rows (broadcast)
            #pragma unroll
            for (int r = 0; r < 4; ++r) {
                float mv = ((float*)&ma)[r];
                ac[r].x = fmaf(mv, wv.x, ac[r].x); ac[r].y = fmaf(mv, wv.y, ac[r].y);
                ac[r].z = fmaf(mv, wv.z, ac[r].z); ac[r].w = fmaf(mv, wv.w, ac[r].w);
            }
        }
        int base = ((sl << 5) + g3) * 20;
        #pragma unroll
        for (int r = 0; r < 4; ++r) *(float4*)&s_part[base + (r << 2)] = ac[r];
    }
    __syncthreads();                              // B6: agg partials ready

    // ---- Phase 5: reduce, bias+relu, residual, LayerNorm (1 output/thread)
    {
        int wh = wave & 1;                        // wave within the 2-wave row group
        float bad = ba[d5], gam = gamma[d5], bet = beta[d5];
        float agg = 0.f;
        #pragma unroll
        for (int s2 = 0; s2 < 16; ++s2)
            agg += s_part[((s2 << 5) + (d5 >> 2)) * 20 + (r5 << 2) + (d5 & 3)];
        float x = node[(size_t)(b * NN + i0 + r5) * DD + d5] + fmaxf(agg + bad, 0.f);
        float s1 = x, s2v = x * x;
        for (int off = 32; off > 0; off >>= 1) {
            s1 += __shfl_xor(s1, off);
            s2v += __shfl_xor(s2v, off);
        }
        if (lane == 0) { s_red2[r5][wh][0] = s1; s_red2[r5][wh][1] = s2v; }
        __syncthreads();                          // B7: LN stats ready
        float t1 = s_red2[r5][0][0] + s_red2[r5][1][0];
        float t2 = s_red2[r5][0][1] + s_red2[r5][1][1];
        float mu  = t1 * (1.0f / DD);
        float var = t2 * (1.0f / DD) - mu * mu;
        float inv = rsqrtf(var + 1e-5f);
        out[(size_t)(b * NN + i0 + r5) * DD + d5] = (x - mu) * inv * gam + bet;
    }
}

extern "C" void kernel_launch(void* const* d_in, const int* in_sizes, int n_in,
                              void* d_out, int out_size, void* d_ws, size_t ws_size,
                              hipStream_t stream) {
    const float* node = (const float*)d_in[0];
    const int*   adj  = (const int*)d_in[1];
    const float* rel  = (const float*)d_in[2];
    const float* Wn   = (const float*)d_in[3];
    const float* bn   = (const float*)d_in[4];
    const float* We1  = (const float*)d_in[5];
    const float* be1  = (const float*)d_in[6];
    const float* We2  = (const float*)d_in[7];
    const float* be2  = (const float*)d_in[8];
    const float* Wa   = (const float*)d_in[9];
    const float* ba   = (const float*)d_in[10];
    const float* gamma = (const float*)d_in[11];
    const float* beta  = (const float*)d_in[12];
    float* out = (float*)d_out;

    float* ws  = (float*)d_ws;
    const int ROWS = BB * NN * DD;              // 262144
    float* h        = ws;                       // f32
    _Float16* tih   = (_Float16*)(ws + ROWS);   // f16
    _Float16* ajh   = tih + ROWS;               // f16
    _Float16* wth   = ajh + ROWS;               // f16, 512 halfs

    prep_kernel<<<BB * NN / PR, 256, 0, stream>>>(node, Wn, bn, We1, be1, We2,
                                                  h, tih, ajh, wth);
    edge_kernel<<<BB * NN / IT, 512, 0, stream>>>(tih, ajh, wth, rel, adj, be2,
                                                  h, Wa, ba, node, gamma, beta, out);
}

// Round 2
// 108.096 us; speedup vs baseline: 1.0214x; 1.0012x over previous
//
#include <hip/hip_runtime.h>
#include <math.h>

#define BB 8
#define NN 256
#define DD 128

typedef _Float16 h2 __attribute__((ext_vector_type(2)));
union U4 { uint4 u; float4 f; h2 h[8]; };

static __device__ __forceinline__ h2 relu2(h2 v) {
    h2 z = {(_Float16)0, (_Float16)0};
#if __has_builtin(__builtin_elementwise_max)
    return __builtin_elementwise_max(v, z);
#else
    v.x = v.x > z.x ? v.x : z.x;
    v.y = v.y > z.y ? v.y : z.y;
    return v;
#endif
}

static __device__ __forceinline__ float dot2acc(h2 a, h2 b, float c) {
#if __has_builtin(__builtin_amdgcn_fdot2)
    return __builtin_amdgcn_fdot2(a, b, c, false);
#else
    return fmaf((float)a.x, (float)b.x, fmaf((float)a.y, (float)b.y, c));
#endif
}

// ---------------- Kernel A: h = node@Wn+bn (f32), ti = node@We1[:D]+be1 (f16),
//                  aj = node@We1[D:2D] (f16). Block 0 also converts edge weights to f16.
// PR=8 rows/block @ 512 threads: halves per-block weight re-reads vs PR=4
// (196 KB/block; 256 blocks -> ~50 MB L2 traffic instead of ~100 MB).
// Thread = (cp = tid&63 col-pair, rp = (tid>>6)&3 row-pair, ks = tid>>8 K-half).
#define PR 8
__global__ __launch_bounds__(512) void prep_kernel(
    const float* __restrict__ node, const float* __restrict__ Wn,
    const float* __restrict__ bn, const float* __restrict__ We1,
    const float* __restrict__ be1, const float* __restrict__ We2,
    float* __restrict__ h, _Float16* __restrict__ tih,
    _Float16* __restrict__ ajh, _Float16* __restrict__ wth)
{
    __shared__ __align__(16) float sx[PR * DD];     // 4 KB
    __shared__ float s_acc[12 * 256];               // 12 KB
    int tid = threadIdx.x;
    int cp = tid & 63;
    int rp = (tid >> 6) & 3;
    int ks = tid >> 8;
    int row0 = blockIdx.x * PR;
    if (tid < 256) {
        int rr = tid >> 5, cc = (tid & 31) << 2;
        *(float4*)&sx[rr * DD + cc] = *(const float4*)&node[(size_t)(row0 + rr) * DD + cc];
    }
    if (blockIdx.x == 0 && tid < 128) {
        wth[0 * 128 + tid] = (_Float16)We1[(size_t)(2 * DD + 0) * DD + tid];
        wth[1 * 128 + tid] = (_Float16)We1[(size_t)(2 * DD + 1) * DD + tid];
        wth[2 * 128 + tid] = (_Float16)We1[(size_t)(2 * DD + 2) * DD + tid];
        wth[3 * 128 + tid] = (_Float16)We2[tid];
    }
    __syncthreads();
    int d0 = cp << 1;
    int ra = rp << 1, rb = ra | 1;
    float ah[2] = {0.f, 0.f}, ai[2] = {0.f, 0.f}, ajc[2] = {0.f, 0.f};
    float bh[2] = {0.f, 0.f}, bi[2] = {0.f, 0.f}, bjc[2] = {0.f, 0.f};
    int k0 = ks << 6;
    for (int k = k0; k < k0 + 64; k += 4) {
        float4 xa = *(const float4*)&sx[ra * DD + k];
        float4 xb = *(const float4*)&sx[rb * DD + k];
        #pragma unroll
        for (int kk = 0; kk < 4; ++kk) {
            float2 w0 = *(const float2*)&Wn [(size_t)(k + kk) * DD + d0];
            float2 w1 = *(const float2*)&We1[(size_t)(k + kk) * DD + d0];
            float2 w2 = *(const float2*)&We1[(size_t)(DD + k + kk) * DD + d0];
            float xav = (kk == 0) ? xa.x : (kk == 1) ? xa.y : (kk == 2) ? xa.z : xa.w;
            float xbv = (kk == 0) ? xb.x : (kk == 1) ? xb.y : (kk == 2) ? xb.z : xb.w;
            ah[0] = fmaf(xav, w0.x, ah[0]); ah[1] = fmaf(xav, w0.y, ah[1]);
            ai[0] = fmaf(xav, w1.x, ai[0]); ai[1] = fmaf(xav, w1.y, ai[1]);
            ajc[0] = fmaf(xav, w2.x, ajc[0]); ajc[1] = fmaf(xav, w2.y, ajc[1]);
            bh[0] = fmaf(xbv, w0.x, bh[0]); bh[1] = fmaf(xbv, w0.y, bh[1]);
            bi[0] = fmaf(xbv, w1.x, bi[0]); bi[1] = fmaf(xbv, w1.y, bi[1]);
            bjc[0] = fmaf(xbv, w2.x, bjc[0]); bjc[1] = fmaf(xbv, w2.y, bjc[1]);
        }
    }
    int p = (rp << 6) | cp;                         // 0..255
    if (ks == 1) {
        s_acc[0 * 256 + p] = ah[0];  s_acc[1 * 256 + p] = ah[1];
        s_acc[2 * 256 + p] = ai[0];  s_acc[3 * 256 + p] = ai[1];
        s_acc[4 * 256 + p] = ajc[0]; s_acc[5 * 256 + p] = ajc[1];
        s_acc[6 * 256 + p] = bh[0];  s_acc[7 * 256 + p] = bh[1];
        s_acc[8 * 256 + p] = bi[0];  s_acc[9 * 256 + p] = bi[1];
        s_acc[10 * 256 + p] = bjc[0]; s_acc[11 * 256 + p] = bjc[1];
    }
    __syncthreads();
    if (ks == 0) {
        float2 bn2  = *(const float2*)&bn[d0];
        float2 be12 = *(const float2*)&be1[d0];
        ah[0] += s_acc[0 * 256 + p] + bn2.x;  ah[1] += s_acc[1 * 256 + p] + bn2.y;
        ai[0] += s_acc[2 * 256 + p] + be12.x; ai[1] += s_acc[3 * 256 + p] + be12.y;
        ajc[0] += s_acc[4 * 256 + p];         ajc[1] += s_acc[5 * 256 + p];
        bh[0] += s_acc[6 * 256 + p] + bn2.x;  bh[1] += s_acc[7 * 256 + p] + bn2.y;
        bi[0] += s_acc[8 * 256 + p] + be12.x; bi[1] += s_acc[9 * 256 + p] + be12.y;
        bjc[0] += s_acc[10 * 256 + p];        bjc[1] += s_acc[11 * 256 + p];
        size_t oa = (size_t)(row0 + ra) * DD + d0;
        size_t ob = (size_t)(row0 + rb) * DD + d0;
        *(float2*)&h[oa] = make_float2(ah[0], ah[1]);
        *(float2*)&h[ob] = make_float2(bh[0], bh[1]);
        *(h2*)&tih[oa] = (h2){(_Float16)ai[0], (_Float16)ai[1]};
        *(h2*)&tih[ob] = (h2){(_Float16)bi[0], (_Float16)bi[1]};
        *(h2*)&ajh[oa] = (h2){(_Float16)ajc[0], (_Float16)ajc[1]};
        *(h2*)&ajh[ob] = (h2){(_Float16)bjc[0], (_Float16)bjc[1]};
    }
}

// ---------------- Kernel B (fused): IT=4 rows/block, 512 threads, grid 512.
// LDS ~70KB -> 2 blocks/CU (4 waves/SIMD) so the serial phase chain of one block
// overlaps the other block's compute. Full 64KB f16 aj tile staged per block;
// thread = (j = tid&255, half = tid>>8 -> rows 2h, 2h+1).
#define IT 4
__global__ __launch_bounds__(512, 4) void edge_kernel(
    const _Float16* __restrict__ tih, const _Float16* __restrict__ ajh,
    const _Float16* __restrict__ wth, const float* __restrict__ rel,
    const int* __restrict__ adj, const float* __restrict__ be2,
    const float* __restrict__ h, const float* __restrict__ Wa,
    const float* __restrict__ ba, const float* __restrict__ node,
    const float* __restrict__ gamma, const float* __restrict__ beta,
    float* __restrict__ out)
{
    __shared__ __align__(16) float s_buf[16384];   // 64KB: f16 aj tile / partial slots alias
    __shared__ __align__(16) float s_w[NN * 4];    // w transposed: [j][r], 4KB
    __shared__ __align__(16) float s_m[DD * 4];    // msg transposed: [k][r], 2KB
    __shared__ float s_redM[IT][4];
    __shared__ float s_redS[IT][4];
    __shared__ float s_red2[IT][2][2];

    int tid = threadIdx.x;
    int b  = blockIdx.x >> 6;                 // 64 blocks per batch
    int i0 = (blockIdx.x & 63) << 2;          // 4 rows
    int j    = tid & 255;
    int half = tid >> 8;                      // 0/1: rows 2*half, 2*half+1
    int rb   = half << 1;

    // ---- per-thread edge inputs for 2 rows
    const float2* rel2 = (const float2*)rel;
    float sc[2];
    int msk[2];
    h2 rxh[2], ryh[2], dsh[2];
    float be2v = be2[0];
    #pragma unroll
    for (int r = 0; r < 2; ++r) {
        float2 rp = rel2[(size_t)(b * NN + i0 + rb + r) * NN + j];
        float ds = sqrtf(rp.x * rp.x + rp.y * rp.y);
        _Float16 xh = (_Float16)rp.x, yh = (_Float16)rp.y, dh = (_Float16)ds;
        rxh[r] = (h2){xh, xh}; ryh[r] = (h2){yh, yh}; dsh[r] = (h2){dh, dh};
        msk[r] = adj[(size_t)(b * NN + i0 + rb + r) * NN + j];
        sc[r] = be2v;
    }

    // ---- stage full f16 aj tile (256 rows x 128 f16 = 64KB), XOR-swizzled 16B granules
    {
        const _Float16* AJH = ajh + (size_t)b * NN * DD;
        #pragma unroll
        for (int it = 0; it < 8; ++it) {
            int idx = tid + (it << 9);         // 0..4095 granules
            int rr = idx >> 4, g = idx & 15;
            float4 v = *(const float4*)&AJH[(size_t)rr * DD + (g << 3)];
            *(float4*)&s_buf[rr * 64 + ((g ^ (rr & 15)) << 2)] = v;
        }
    }
    // wave-uniform ti base -> scalar loads
    int tibase = __builtin_amdgcn_readfirstlane((b * NN + i0 + rb) * DD);
    const _Float16* TIH = tih + tibase;
    __syncthreads();                              // B0: tile ready

    // ---- Phase 1: scores (packed f16)
    #pragma unroll 4
    for (int gg = 0; gg < 16; ++gg) {
        U4 a; a.f = *(const float4*)&s_buf[j * 64 + ((gg ^ (j & 15)) << 2)];
        int dd = gg << 3;
        U4 w0u, w1u, w2u, e2u;
        w0u.u = *(const uint4*)&wth[0 * 128 + dd];
        w1u.u = *(const uint4*)&wth[1 * 128 + dd];
        w2u.u = *(const uint4*)&wth[2 * 128 + dd];
        e2u.u = *(const uint4*)&wth[3 * 128 + dd];
        #pragma unroll
        for (int r = 0; r < 2; ++r) {
            U4 t; t.u = *(const uint4*)&TIH[r * DD + dd];
            #pragma unroll
            for (int u = 0; u < 4; ++u) {
                h2 v = t.h[u] + a.h[u];
                v = rxh[r] * w0u.h[u] + v;
                v = ryh[r] * w1u.h[u] + v;
                v = dsh[r] * w2u.h[u] + v;
                v = relu2(v);
                sc[r] = dot2acc(v, e2u.h[u], sc[r]);
            }
        }
    }
    #pragma unroll
    for (int r = 0; r < 2; ++r) if (msk[r] == 0) sc[r] = -3.0e38f;

    // ---- Phase 2: masked softmax across j (4 waves per half)
    int wave = tid >> 6, wig = wave & 3, lane = tid & 63;
    float e[2];
    {
        float m[2];
        #pragma unroll
        for (int r = 0; r < 2; ++r) m[r] = sc[r];
        for (int off = 32; off > 0; off >>= 1) {
            #pragma unroll
            for (int r = 0; r < 2; ++r) m[r] = fmaxf(m[r], __shfl_xor(m[r], off));
        }
        if (lane == 0) {
            #pragma unroll
            for (int r = 0; r < 2; ++r) s_redM[rb + r][wig] = m[r];
        }
    }
    __syncthreads();                              // B1: maxes ready
    {
        float s[2];
        #pragma unroll
        for (int r = 0; r < 2; ++r) {
            float M = fmaxf(fmaxf(s_redM[rb + r][0], s_redM[rb + r][1]),
                            fmaxf(s_redM[rb + r][2], s_redM[rb + r][3]));
            e[r] = (msk[r] == 0) ? 0.f : __expf(sc[r] - M);
            s[r] = e[r];
        }
        for (int off = 32; off > 0; off >>= 1) {
            #pragma unroll
            for (int r = 0; r < 2; ++r) s[r] += __shfl_xor(s[r], off);
        }
        if (lane == 0) {
            #pragma unroll
            for (int r = 0; r < 2; ++r) s_redS[rb + r][wig] = s[r];
        }
    }
    __syncthreads();                              // B2: sums ready
    {
        float2 wq;
        #pragma unroll
        for (int r = 0; r < 2; ++r) {
            float S = s_redS[rb + r][0] + s_redS[rb + r][1] + s_redS[rb + r][2] + s_redS[rb + r][3];
            float wv = e[r] * __builtin_amdgcn_rcpf(S);
            ((float*)&wq)[r] = wv;
        }
        *(float2*)&s_w[(j << 2) + rb] = wq;       // [j][4 rows]
    }
    __syncthreads();                              // B3: s_w ready; tile dead (s_part alias safe)

    // ---- Phase 3: msg partials = w@h. Thread: g3=tid&31 (d4-group), sl=tid>>5 (16 j-slices of 16)
    float* s_part = s_buf;                        // stride-20 slots (80B, 16B-aligned)
    int g3 = tid & 31, sl = tid >> 5;
    {
        const float* hb = h + (size_t)b * NN * DD;
        float4 acc[4];
        #pragma unroll
        for (int r = 0; r < 4; ++r) acc[r] = make_float4(0.f, 0.f, 0.f, 0.f);
        for (int q = 0; q < 16; ++q) {
            int jj = (sl << 4) + q;
            float4 hv = *(const float4*)&hb[(size_t)jj * DD + (g3 << 2)];
            float4 wa = *(const float4*)&s_w[jj << 2];     // rows 0-3 (broadcast)
            #pragma unroll
            for (int r = 0; r < 4; ++r) {
                float wv = ((float*)&wa)[r];
                acc[r].x = fmaf(wv, hv.x, acc[r].x); acc[r].y = fmaf(wv, hv.y, acc[r].y);
                acc[r].z = fmaf(wv, hv.z, acc[r].z); acc[r].w = fmaf(wv, hv.w, acc[r].w);
            }
        }
        int base = ((sl << 5) + g3) * 20;
        #pragma unroll
        for (int r = 0; r < 4; ++r) *(float4*)&s_part[base + (r << 2)] = acc[r];
    }
    __syncthreads();                              // B4: partials ready
    int r5 = tid >> 7, d5 = tid & 127;
    {
        float s = 0.f;
        #pragma unroll
        for (int s2 = 0; s2 < 16; ++s2)
            s += s_part[((s2 << 5) + (d5 >> 2)) * 20 + (r5 << 2) + (d5 & 3)];
        s_m[(d5 << 2) + r5] = s;
    }
    __syncthreads();                              // B5: s_m ready; s_part reads done

    // ---- Phase 4: agg partials = msg@Wa. Thread: g3 (d4-group), sl (16 k-slices of 8)
    {
        float4 ac[4];
        #pragma unroll
        for (int r = 0; r < 4; ++r) ac[r] = make_float4(0.f, 0.f, 0.f, 0.f);
        for (int q = 0; q < 8; ++q) {
            int k = (sl << 3) + q;
            float4 wv = *(const float4*)&Wa[(size_t)k * DD + (g3 << 2)];
            float4 ma = *(const float4*)&s_m[k << 2];      // 4 rows (broadcast)
            #pragma unroll
            for (int r = 0; r < 4; ++r) {
                float mv = ((float*)&ma)[r];
                ac[r].x = fmaf(mv, wv.x, ac[r].x); ac[r].y = fmaf(mv, wv.y, ac[r].y);
                ac[r].z = fmaf(mv, wv.z, ac[r].z); ac[r].w = fmaf(mv, wv.w, ac[r].w);
            }
        }
        int base = ((sl << 5) + g3) * 20;
        #pragma unroll
        for (int r = 0; r < 4; ++r) *(float4*)&s_part[base + (r << 2)] = ac[r];
    }
    __syncthreads();                              // B6: agg partials ready

    // ---- Phase 5: reduce, bias+relu, residual, LayerNorm (1 output/thread)
    {
        int wh = wave & 1;                        // wave within the 2-wave row group
        float bad = ba[d5], gam = gamma[d5], bet = beta[d5];
        float agg = 0.f;
        #pragma unroll
        for (int s2 = 0; s2 < 16; ++s2)
            agg += s_part[((s2 << 5) + (d5 >> 2)) * 20 + (r5 << 2) + (d5 & 3)];
        float x = node[(size_t)(b * NN + i0 + r5) * DD + d5] + fmaxf(agg + bad, 0.f);
        float s1 = x, s2v = x * x;
        for (int off = 32; off > 0; off >>= 1) {
            s1 += __shfl_xor(s1, off);
            s2v += __shfl_xor(s2v, off);
        }
        if (lane == 0) { s_red2[r5][wh][0] = s1; s_red2[r5][wh][1] = s2v; }
        __syncthreads();                          // B7: LN stats ready
        float t1 = s_red2[r5][0][0] + s_red2[r5][1][0];
        float t2 = s_red2[r5][0][1] + s_red2[r5][1][1];
        float mu  = t1 * (1.0f / DD);
        float var = t2 * (1.0f / DD) - mu * mu;
        float inv = rsqrtf(var + 1e-5f);
        out[(size_t)(b * NN + i0 + r5) * DD + d5] = (x - mu) * inv * gam + bet;
    }
}

extern "C" void kernel_launch(void* const* d_in, const int* in_sizes, int n_in,
                              void* d_out, int out_size, void* d_ws, size_t ws_size,
                              hipStream_t stream) {
    const float* node = (const float*)d_in[0];
    const int*   adj  = (const int*)d_in[1];
    const float* rel  = (const float*)d_in[2];
    const float* Wn   = (const float*)d_in[3];
    const float* bn   = (const float*)d_in[4];
    const float* We1  = (const float*)d_in[5];
    const float* be1  = (const float*)d_in[6];
    const float* We2  = (const float*)d_in[7];
    const float* be2  = (const float*)d_in[8];
    const float* Wa   = (const float*)d_in[9];
    const float* ba   = (const float*)d_in[10];
    const float* gamma = (const float*)d_in[11];
    const float* beta  = (const float*)d_in[12];
    float* out = (float*)d_out;

    float* ws  = (float*)d_ws;
    const int ROWS = BB * NN * DD;              // 262144
    float* h        = ws;                       // f32
    _Float16* tih   = (_Float16*)(ws + ROWS);   // f16
    _Float16* ajh   = tih + ROWS;               // f16
    _Float16* wth   = ajh + ROWS;               // f16, 512 halfs

    prep_kernel<<<BB * NN / PR, 512, 0, stream>>>(node, Wn, bn, We1, be1, We2,
                                                  h, tih, ajh, wth);
    edge_kernel<<<BB * NN / IT, 512, 0, stream>>>(tih, ajh, wth, rel, adj, be2,
                                                  h, Wa, ba, node, gamma, beta, out);
}